// Round 13
// baseline (231.834 us; speedup 1.0000x reference)
//
#include <hip/hip_runtime.h>
#include <math.h>

#define S_LEN 4096
#define DM    1024
#define NHEAD 16
#define HDIM  64
#define C3    3072   // 3 * DM

typedef __attribute__((ext_vector_type(8))) short bf8_t;    // 8 bf16
typedef __attribute__((ext_vector_type(4))) float f32x4;
typedef __attribute__((ext_vector_type(16))) float f32x16;

__device__ __forceinline__ short f2bf(float f) {
    union { float f; unsigned u; } v; v.f = f;
    unsigned r = v.u + 0x7FFF + ((v.u >> 16) & 1);   // RNE, finite inputs
    return (short)(r >> 16);
}
__device__ __forceinline__ float fexp2(float x) { return __builtin_amdgcn_exp2f(x); }

// HW packed fp32->bf16x2 convert (RNE). One VALU op replaces ~10.
__device__ __forceinline__ unsigned cvtpk(float a, float b) {
    unsigned r;
    asm("v_cvt_pk_bf16_f32 %0, %1, %2" : "=v"(r) : "v"(a), "v"(b));
    return r;
}

__device__ __forceinline__ void gload_lds16(const void* g, void* l) {
    __builtin_amdgcn_global_load_lds(
        (const __attribute__((address_space(1))) unsigned int*)g,
        (__attribute__((address_space(3))) unsigned int*)l, 16, 0, 0);
}

// tree sum over f32x16 (short dependency chains)
__device__ __forceinline__ float vsum16(f32x16 s) {
    float a = (s[0] + s[1]) + (s[2] + s[3]);
    float b = (s[4] + s[5]) + (s[6] + s[7]);
    float c = (s[8] + s[9]) + (s[10] + s[11]);
    float d = (s[12] + s[13]) + (s[14] + s[15]);
    return (a + b) + (c + d);
}

// ---------------------------------------------------------------------------
// Elementwise fp32 -> bf16 cast (8 elems/thread).
// ---------------------------------------------------------------------------
__global__ void cast_f32_bf16(const float* __restrict__ in, short* __restrict__ out, int n8)
{
    int i = blockIdx.x * blockDim.x + threadIdx.x;
    if (i < n8) {
        float4 a = ((const float4*)in)[i * 2];
        float4 b = ((const float4*)in)[i * 2 + 1];
        bf8_t v = {f2bf(a.x), f2bf(a.y), f2bf(a.z), f2bf(a.w),
                   f2bf(b.x), f2bf(b.y), f2bf(b.z), f2bf(b.w)};
        ((bf8_t*)out)[i] = v;
    }
}

// ---------------------------------------------------------------------------
// Transpose + cast: in [R][C] fp32 -> out [C][R] bf16.  32x32 tiles.
// ---------------------------------------------------------------------------
__global__ __launch_bounds__(256)
void transpose_cast(const float* __restrict__ in, short* __restrict__ out, int R, int C)
{
    __shared__ float t[32][33];
    const int tx = threadIdx.x & 31;
    const int ty = threadIdx.x >> 5;      // 0..7
    const int r0 = blockIdx.y * 32;
    const int c0 = blockIdx.x * 32;
    #pragma unroll
    for (int i = 0; i < 32; i += 8)
        t[ty + i][tx] = in[(size_t)(r0 + ty + i) * C + c0 + tx];
    __syncthreads();
    #pragma unroll
    for (int i = 0; i < 32; i += 8)
        out[(size_t)(c0 + ty + i) * R + r0 + tx] = f2bf(t[tx][ty + i]);
}

// ---------------------------------------------------------------------------
// Transpose V out of qkv: per (b,h): [4096 s][64 d] -> vt[bh][64 d][4096 s].
// ---------------------------------------------------------------------------
__global__ __launch_bounds__(256)
void transpose_v(const short* __restrict__ qkv, short* __restrict__ vt)
{
    __shared__ short t[64][72];
    const int st = blockIdx.x, bh = blockIdx.y;
    const int b = bh >> 4, h = bh & 15;
    const int tid = threadIdx.x;
    const int r   = tid >> 2;            // 0..63
    const int c16 = (tid & 3) * 16;
    const short* src = qkv + (size_t)b * S_LEN * C3 + 2 * DM + h * HDIM;
    const short* sp  = src + (size_t)(st * 64 + r) * C3 + c16;
    *(bf8_t*)&t[r][c16]     = *(const bf8_t*)sp;
    *(bf8_t*)&t[r][c16 + 8] = *(const bf8_t*)(sp + 8);
    __syncthreads();
    short tmp[16];
    #pragma unroll
    for (int i = 0; i < 16; ++i) tmp[i] = t[c16 + i][r];
    short* dp = vt + (size_t)bh * HDIM * S_LEN + (size_t)r * S_LEN + st * 64 + c16;
    *(bf8_t*)dp       = *(bf8_t*)&tmp[0];
    *(bf8_t*)(dp + 8) = *(bf8_t*)&tmp[8];
}

// ---------------------------------------------------------------------------
// bf16 MFMA GEMM (m97 structure) — verified rounds 3-12, unchanged.
// ---------------------------------------------------------------------------
template<bool BF16OUT>
__global__ __launch_bounds__(256)
void gemm_mfma(const short* __restrict__ A, const short* __restrict__ Bt,
               const float* __restrict__ bias, void* __restrict__ Cout,
               int M, int N)
{
    constexpr int K = 1024;
    __shared__ __align__(16) short As[128 * 64];
    __shared__ __align__(16) short Bs[128 * 64];

    const int nbx = N / 128;
    const int nwg = (M / 128) * nbx;
    int bid = blockIdx.x;
    bid = (bid & 7) * (nwg >> 3) + (bid >> 3);
    const int by = bid / nbx, bx = bid % nbx;
    const int row0 = by * 128, col0 = bx * 128;

    const int tid  = threadIdx.x;
    const int lane = tid & 63;
    const int w    = tid >> 6;
    const int l15  = lane & 15;
    const int l4   = lane >> 4;
    const int wr   = w >> 1, wc = w & 1;

    f32x4 acc[4][4];
    #pragma unroll
    for (int i = 0; i < 4; ++i)
        #pragma unroll
        for (int j = 0; j < 4; ++j) acc[i][j] = (f32x4){0.f, 0.f, 0.f, 0.f};

    size_t goff[4];
    int    loff[4];
    #pragma unroll
    for (int i = 0; i < 4; ++i) {
        const int o   = (w * 4 + i) * 1024 + lane * 16;
        const int row = o >> 7;
        const int col = (o & 127) ^ ((row & 7) << 4);
        goff[i] = (size_t)row * (K * 2) + col;
        loff[i] = o;
    }
    const char* Ab = (const char*)A  + (size_t)row0 * (K * 2);
    const char* Bb = (const char*)Bt + (size_t)col0 * (K * 2);

    for (int k0 = 0; k0 < K; k0 += 64) {
        __syncthreads();
        #pragma unroll
        for (int i = 0; i < 4; ++i) {
            gload_lds16(Ab + goff[i] + k0 * 2, (char*)As + loff[i]);
            gload_lds16(Bb + goff[i] + k0 * 2, (char*)Bs + loff[i]);
        }
        __syncthreads();

        #pragma unroll
        for (int ks = 0; ks < 2; ++ks) {
            bf8_t af[4], bfr[4];
            #pragma unroll
            for (int mi = 0; mi < 4; ++mi) {
                const int row = wr * 64 + mi * 16 + l15;
                const int off = (row * 128 + ks * 64 + l4 * 16) ^ ((row & 7) << 4);
                af[mi] = *(bf8_t*)((char*)As + off);
            }
            #pragma unroll
            for (int ni = 0; ni < 4; ++ni) {
                const int row = wc * 64 + ni * 16 + l15;
                const int off = (row * 128 + ks * 64 + l4 * 16) ^ ((row & 7) << 4);
                bfr[ni] = *(bf8_t*)((char*)Bs + off);
            }
            #pragma unroll
            for (int mi = 0; mi < 4; ++mi)
                #pragma unroll
                for (int ni = 0; ni < 4; ++ni)
                    acc[mi][ni] = __builtin_amdgcn_mfma_f32_16x16x32_bf16(
                        af[mi], bfr[ni], acc[mi][ni], 0, 0, 0);
        }
    }

    float bv[4];
    #pragma unroll
    for (int ni = 0; ni < 4; ++ni)
        bv[ni] = bias[col0 + wc * 64 + ni * 16 + l15];

    #pragma unroll
    for (int mi = 0; mi < 4; ++mi)
        #pragma unroll
        for (int r = 0; r < 4; ++r) {
            const int row = row0 + wr * 64 + mi * 16 + l4 * 4 + r;
            #pragma unroll
            for (int ni = 0; ni < 4; ++ni) {
                const int col = col0 + wc * 64 + ni * 16 + l15;
                const float val = acc[mi][ni][r] + bv[ni];
                if constexpr (BF16OUT)
                    ((short*)Cout)[(size_t)row * N + col] = f2bf(val);
                else
                    ((float*)Cout)[(size_t)row * N + col] = val;
            }
        }
}

// ---------------------------------------------------------------------------
// Flash attention, swapped-QK^T 32x32x16 MFMA.
// Round-13: r12 (fixed-m, XCD-grouped, paired q-tiles) + CROSS-TILE SOFTWARE
// PIPELINE (T15): PV is delayed one tile. Iteration kt issues QK^T(kt) then
// immediately PV(kt-1) from registers packed (and pre-exchanged) last
// iteration — MFMA bursts are back-to-back and exp/pack(kt) overlaps PV's
// execution. Legal because fixed-m makes tile contributions commutative.
// 3-buffer LDS rotation (48KB) since PV reads V one tile behind staging.
// Drain PV after the loop for waves with nkt_w == nkt.
// ---------------------------------------------------------------------------
__global__ __launch_bounds__(256)
void attn_mfma32(const short* __restrict__ qkv, const short* __restrict__ vt,
                 short* __restrict__ out)
{
    // XCD grouping: consecutive dispatch ids round-robin XCDs (lin % 8).
    const int lin = blockIdx.x + 16 * blockIdx.y;   // HW dispatch order
    const int xcd = lin & 7;
    const int idx = lin >> 3;                       // 0..63 within XCD
    const int bh  = xcd * 4 + (idx >> 4);           // 4 heads per XCD
    const int g   = idx & 15;                       // pair index 0..15

    const int b   = bh >> 4, h = bh & 15;
    const int tid = threadIdx.x;
    const int lane = tid & 63;
    const int w    = tid >> 6;       // wave 0..3
    const int l31  = lane & 31;
    const int hi   = lane >> 5;      // 0/1

    __shared__ __align__(16) char lds[3][16384];   // 3 bufs x [K 8KB | V 8KB]

    const float C   = 0.125f * 1.44269504f;         // scale * log2(e)
    const float NEG = -1e30f;

    const short* qkb = qkv + (size_t)b * S_LEN * C3 + h * HDIM;

    // staging (inverse-swizzled source, linear LDS dest); 4 loads/thread
    const int sr = tid >> 3;                                  // row 0..31
    const int sc = ((tid & 7) * 16) ^ ((sr & 7) << 4);        // swizzled byte col
    const char* srcK = (const char*)(qkb + DM) + (size_t)sr * (C3 * 2) + sc;
    const char* srcV = (const char*)(vt + (size_t)bh * HDIM * S_LEN)
                       + (size_t)sr * (S_LEN * 2) + sc;
    const int ldst = tid * 16;                                // 0..4095

    #pragma unroll 1
    for (int half = 0; half < 2; ++half) {
        const int qb     = half ? g : (31 - g);     // heavy tile first
        const int Q0     = qb * 128;
        const int nkt    = qb * 2 + 2;              // block trip count
        const int qmin_w = Q0 + w * 32;
        const int qmax_w = qmin_w + 31;
        const int q_g    = qmin_w + l31;            // this lane's q row
        const int nkt_w  = (qmax_w >> 6) + 1;       // wave's active tiles

        // ---- Q fragments (B-operand): col=q=l31, d = 16*ds + 8*hi + j ----
        bf8_t qf[4];
        {
            const short* qp = qkb + (size_t)q_g * C3 + hi * 8;
            qf[0] = *(const bf8_t*)(qp);
            qf[1] = *(const bf8_t*)(qp + 16);
            qf[2] = *(const bf8_t*)(qp + 32);
            qf[3] = *(const bf8_t*)(qp + 48);
        }

        f32x16 o0, o1;
        #pragma unroll
        for (int r = 0; r < 16; ++r) { o0[r] = 0.f; o1[r] = 0.f; }
        float l = 0.f;           // lane-local half-sum; combined in epilogue
        unsigned Pf[4][4];       // pre-exchanged packed P of PREVIOUS tile

        // prologue: stage kt=0 into buf0
        gload_lds16(srcK,                     lds[0] + ldst);
        gload_lds16(srcK + 32 * (C3 * 2),     lds[0] + 4096 + ldst);
        gload_lds16(srcV,                     lds[0] + 8192 + ldst);
        gload_lds16(srcV + 32 * (S_LEN * 2),  lds[0] + 12288 + ldst);
        __syncthreads();

        int cur = 0;
        #pragma unroll 1
        for (int kt = 0; kt < nkt; ++kt) {
            const int nxt = (cur == 2) ? 0 : cur + 1;
            const int prv = (cur == 0) ? 2 : cur - 1;

            // stage next tile (flies during compute; lands before barrier)
            if (kt + 1 < nkt) {
                const char* sK = srcK + (size_t)(kt + 1) * 64 * (C3 * 2);
                const char* sV = srcV + (size_t)(kt + 1) * 64 * 2;
                char* d = lds[nxt];
                gload_lds16(sK,                    d + ldst);
                gload_lds16(sK + 32 * (C3 * 2),    d + 4096 + ldst);
                gload_lds16(sV,                    d + 8192 + ldst);
                gload_lds16(sV + 32 * (S_LEN * 2), d + 12288 + ldst);
            }

            const bool doqk = (kt < nkt_w);
            f32x16 s0, s1;

            // ---- QK^T(kt): S^T = mfma(K, Q) ----
            if (doqk) {
                const char* Kb = lds[cur];
                #pragma unroll
                for (int r = 0; r < 16; ++r) { s0[r] = 0.f; s1[r] = NEG; }
                __builtin_amdgcn_s_setprio(1);
                #pragma unroll
                for (int ds = 0; ds < 4; ++ds) {
                    const int R0 = l31;
                    const int off0 = (R0 * 128 + ds * 32 + hi * 16) ^ ((R0 & 7) << 4);
                    bf8_t kf = *(const bf8_t*)(Kb + off0);
                    s0 = __builtin_amdgcn_mfma_f32_32x32x16_bf16(kf, qf[ds], s0, 0, 0, 0);
                }
                const int kb0 = kt * 64;
                if ((kb0 + 32) <= qmax_w) {
                    #pragma unroll
                    for (int r = 0; r < 16; ++r) s1[r] = 0.f;
                    #pragma unroll
                    for (int ds = 0; ds < 4; ++ds) {
                        const int R1 = 32 + l31;
                        const int off1 = (R1 * 128 + ds * 32 + hi * 16) ^ ((R1 & 7) << 4);
                        bf8_t kf = *(const bf8_t*)(Kb + off1);
                        s1 = __builtin_amdgcn_mfma_f32_32x32x16_bf16(kf, qf[ds], s1, 0, 0, 0);
                    }
                }
                __builtin_amdgcn_s_setprio(0);
            }

            // ---- PV(kt-1): pure LDS-load + MFMA from pre-exchanged Pf ----
            if (kt >= 1 && kt <= nkt_w) {
                const char* Vb = lds[prv] + 8192;
                __builtin_amdgcn_s_setprio(1);
                #pragma unroll
                for (int c = 0; c < 4; ++c) {
                    union { unsigned u[4]; bf8_t v; } pf;
                    pf.u[0] = Pf[c][0];
                    pf.u[1] = Pf[c][1];
                    pf.u[2] = Pf[c][2];
                    pf.u[3] = Pf[c][3];
                    {
                        const int R = l31;
                        const int off = (R * 128 + c * 32 + hi * 16) ^ ((R & 7) << 4);
                        bf8_t vf = *(const bf8_t*)(Vb + off);
                        o0 = __builtin_amdgcn_mfma_f32_32x32x16_bf16(pf.v, vf, o0, 0, 0, 0);
                    }
                    {
                        const int R = 32 + l31;
                        const int off = (R * 128 + c * 32 + hi * 16) ^ ((R & 7) << 4);
                        bf8_t vf = *(const bf8_t*)(Vb + off);
                        o1 = __builtin_amdgcn_mfma_f32_32x32x16_bf16(pf.v, vf, o1, 0, 0, 0);
                    }
                }
                __builtin_amdgcn_s_setprio(0);
            }

            // ---- mask + exp + sum + pack(+exchange) for tile kt ----
            if (doqk) {
                const int kb0 = kt * 64;
                if (kb0 + 31 > qmin_w) {
                    #pragma unroll
                    for (int r = 0; r < 16; ++r) {
                        const int k = kb0 + 4 * hi + ((r & 3) + 8 * (r >> 2));
                        if (k > q_g) s0[r] = NEG;
                    }
                }
                if (((kb0 + 32) <= qmax_w) && (kb0 + 63 > qmin_w)) {
                    #pragma unroll
                    for (int r = 0; r < 16; ++r) {
                        const int k = kb0 + 32 + 4 * hi + ((r & 3) + 8 * (r >> 2));
                        if (k > q_g) s1[r] = NEG;
                    }
                }

                // fixed-shift numerator: p = exp2(C*s); masked -> exactly 0
                #pragma unroll
                for (int r = 0; r < 16; ++r) s0[r] = fexp2(s0[r] * C);
                #pragma unroll
                for (int r = 0; r < 16; ++r) s1[r] = fexp2(s1[r] * C);

                l += vsum16(s0) + vsum16(s1);

                unsigned W0[2][4], W1[2][4];
                #pragma unroll
                for (int gg = 0; gg < 4; ++gg) {
                    W0[0][gg] = cvtpk(s0[4 * gg], s0[4 * gg + 1]);
                    W1[0][gg] = cvtpk(s0[4 * gg + 2], s0[4 * gg + 3]);
                    W0[1][gg] = cvtpk(s1[4 * gg], s1[4 * gg + 1]);
                    W1[1][gg] = cvtpk(s1[4 * gg + 2], s1[4 * gg + 3]);
                }
                #pragma unroll
                for (int c = 0; c < 4; ++c) {
                    const int t  = c >> 1;
                    const int gA = 2 * (c & 1);
                    const int gB = gA + 1;
                    const unsigned rx0 = __shfl_xor(hi ? W0[t][gA] : W0[t][gB], 32);
                    const unsigned rx1 = __shfl_xor(hi ? W1[t][gA] : W1[t][gB], 32);
                    Pf[c][0] = hi ? rx0 : W0[t][gA];
                    Pf[c][1] = hi ? rx1 : W1[t][gA];
                    Pf[c][2] = hi ? W0[t][gB] : rx0;
                    Pf[c][3] = hi ? W1[t][gB] : rx1;
                }
            }

            __syncthreads();   // staged loads drained; all LDS reads done
            cur = nxt;
        }

        // ---- drain: PV of last tile (only waves whose PV didn't run) ----
        if (nkt_w == nkt) {
            const int prv = (cur == 0) ? 2 : cur - 1;   // buffer of tile nkt-1
            const char* Vb = lds[prv] + 8192;
            #pragma unroll
            for (int c = 0; c < 4; ++c) {
                union { unsigned u[4]; bf8_t v; } pf;
                pf.u[0] = Pf[c][0];
                pf.u[1] = Pf[c][1];
                pf.u[2] = Pf[c][2];
                pf.u[3] = Pf[c][3];
                {
                    const int R = l31;
                    const int off = (R * 128 + c * 32 + hi * 16) ^ ((R & 7) << 4);
                    bf8_t vf = *(const bf8_t*)(Vb + off);
                    o0 = __builtin_amdgcn_mfma_f32_32x32x16_bf16(pf.v, vf, o0, 0, 0, 0);
                }
                {
                    const int R = 32 + l31;
                    const int off = (R * 128 + c * 32 + hi * 16) ^ ((R & 7) << 4);
                    bf8_t vf = *(const bf8_t*)(Vb + off);
                    o1 = __builtin_amdgcn_mfma_f32_32x32x16_bf16(pf.v, vf, o1, 0, 0, 0);
                }
            }
        }

        // ---- epilogue: combine half-sums, normalize, store ----
        const float lt = l + __shfl_xor(l, 32);
        const float inv = 1.f / lt;
        #pragma unroll
        for (int r = 0; r < 16; ++r) {
            const int cr = 4 * hi + ((r & 3) + 8 * (r >> 2));
            const float iv = __shfl(inv, cr);
            const int row = Q0 + w * 32 + cr;
            short* op = out + (size_t)(b * S_LEN + row) * DM + h * HDIM + l31;
            op[0]  = f2bf(o0[r] * iv);
            op[32] = f2bf(o1[r] * iv);
        }

        __syncthreads();   // drain-PV LDS reads done before next half stages
    }
}

// ---------------------------------------------------------------------------
extern "C" void kernel_launch(void* const* d_in, const int* in_sizes, int n_in,
                              void* d_out, int out_size, void* d_ws, size_t ws_size,
                              hipStream_t stream)
{
    const float* x     = (const float*)d_in[0];
    const float* w_qkv = (const float*)d_in[1];
    const float* b_qkv = (const float*)d_in[2];
    const float* w_out = (const float*)d_in[3];
    const float* b_out = (const float*)d_in[4];
    float* out = (float*)d_out;

    const int M = 2 * S_LEN;   // 8192 tokens

    char* ws = (char*)d_ws;
    short* qkvb  = (short*)(ws);                    // [8192,3072] bf16  50.3MB
    short* attnb = (short*)(ws + 50331648);         // [8192,1024] bf16  16.8MB
    short* xb    = (short*)(ws + 67108864);         // [8192,1024] bf16  16.8MB
    short* wqkvT = (short*)(ws + 83886080);         // [3072,1024] bf16   6.3MB
    short* woutT = (short*)(ws + 90177536);         // [1024,1024] bf16   2.1MB
    short* vtb   = (short*)(ws + 92274688);         // [32][64][4096]    16.8MB

    // 0) casts / transposes to bf16
    cast_f32_bf16<<<dim3((M * DM / 8 + 255) / 256), 256, 0, stream>>>(x, xb, M * DM / 8);
    transpose_cast<<<dim3(C3 / 32, DM / 32), 256, 0, stream>>>(w_qkv, wqkvT, DM, C3);
    transpose_cast<<<dim3(DM / 32, DM / 32), 256, 0, stream>>>(w_out, woutT, DM, DM);

    // 1) QKV projection (bf16 MFMA) -> bf16
    gemm_mfma<true><<<dim3((M / 128) * (C3 / 128)), 256, 0, stream>>>(
        xb, wqkvT, b_qkv, qkvb, M, C3);

    // 1b) V -> V^T layout for attention staging
    transpose_v<<<dim3(S_LEN / 64, 2 * NHEAD), 256, 0, stream>>>(qkvb, vtb);

    // 2) causal flash attention (pipelined PV, fixed-m, XCD-grouped) -> bf16
    attn_mfma32<<<dim3(16, 2 * NHEAD), 256, 0, stream>>>(qkvb, vtb, attnb);

    // 3) output projection (bf16 MFMA) -> fp32
    gemm_mfma<false><<<dim3((M / 128) * (DM / 128)), 256, 0, stream>>>(
        attnb, woutT, b_out, out, M, DM);
}

// Round 15
// 217.729 us; speedup vs baseline: 1.0648x; 1.0648x over previous
//
#include <hip/hip_runtime.h>
#include <math.h>

#define S_LEN 4096
#define DM    1024
#define NHEAD 16
#define HDIM  64
#define C3    3072   // 3 * DM
#define CL2E  0.180336880f   // (1/sqrt(64)) * log2(e), folded into Q at proj

typedef __attribute__((ext_vector_type(8))) short bf8_t;    // 8 bf16
typedef __attribute__((ext_vector_type(4))) float f32x4;
typedef __attribute__((ext_vector_type(16))) float f32x16;

__device__ __forceinline__ short f2bf(float f) {
    union { float f; unsigned u; } v; v.f = f;
    unsigned r = v.u + 0x7FFF + ((v.u >> 16) & 1);   // RNE, finite inputs
    return (short)(r >> 16);
}
__device__ __forceinline__ float fexp2(float x) { return __builtin_amdgcn_exp2f(x); }

// HW packed fp32->bf16x2 convert (RNE). One VALU op replaces ~10.
__device__ __forceinline__ unsigned cvtpk(float a, float b) {
    unsigned r;
    asm("v_cvt_pk_bf16_f32 %0, %1, %2" : "=v"(r) : "v"(a), "v"(b));
    return r;
}

__device__ __forceinline__ void gload_lds16(const void* g, void* l) {
    __builtin_amdgcn_global_load_lds(
        (const __attribute__((address_space(1))) unsigned int*)g,
        (__attribute__((address_space(3))) unsigned int*)l, 16, 0, 0);
}

// tree sum over f32x16 (short dependency chains)
__device__ __forceinline__ float vsum16(f32x16 s) {
    float a = (s[0] + s[1]) + (s[2] + s[3]);
    float b = (s[4] + s[5]) + (s[6] + s[7]);
    float c = (s[8] + s[9]) + (s[10] + s[11]);
    float d = (s[12] + s[13]) + (s[14] + s[15]);
    return (a + b) + (c + d);
}

// ---------------------------------------------------------------------------
// Elementwise fp32 -> bf16 cast (8 elems/thread).
// ---------------------------------------------------------------------------
__global__ void cast_f32_bf16(const float* __restrict__ in, short* __restrict__ out, int n8)
{
    int i = blockIdx.x * blockDim.x + threadIdx.x;
    if (i < n8) {
        float4 a = ((const float4*)in)[i * 2];
        float4 b = ((const float4*)in)[i * 2 + 1];
        bf8_t v = {f2bf(a.x), f2bf(a.y), f2bf(a.z), f2bf(a.w),
                   f2bf(b.x), f2bf(b.y), f2bf(b.z), f2bf(b.w)};
        ((bf8_t*)out)[i] = v;
    }
}

// ---------------------------------------------------------------------------
// Transpose + cast: in [R][C] fp32 -> out [C][R] bf16.  32x32 tiles.
// ---------------------------------------------------------------------------
__global__ __launch_bounds__(256)
void transpose_cast(const float* __restrict__ in, short* __restrict__ out, int R, int C)
{
    __shared__ float t[32][33];
    const int tx = threadIdx.x & 31;
    const int ty = threadIdx.x >> 5;      // 0..7
    const int r0 = blockIdx.y * 32;
    const int c0 = blockIdx.x * 32;
    #pragma unroll
    for (int i = 0; i < 32; i += 8)
        t[ty + i][tx] = in[(size_t)(r0 + ty + i) * C + c0 + tx];
    __syncthreads();
    #pragma unroll
    for (int i = 0; i < 32; i += 8)
        out[(size_t)(c0 + ty + i) * R + r0 + tx] = f2bf(t[tx][ty + i]);
}

// ---------------------------------------------------------------------------
// Transpose V out of qkv: per (b,h): [4096 s][64 d] -> vt[bh][64 d][4096 s].
// ---------------------------------------------------------------------------
__global__ __launch_bounds__(256)
void transpose_v(const short* __restrict__ qkv, short* __restrict__ vt)
{
    __shared__ short t[64][72];
    const int st = blockIdx.x, bh = blockIdx.y;
    const int b = bh >> 4, h = bh & 15;
    const int tid = threadIdx.x;
    const int r   = tid >> 2;            // 0..63
    const int c16 = (tid & 3) * 16;
    const short* src = qkv + (size_t)b * S_LEN * C3 + 2 * DM + h * HDIM;
    const short* sp  = src + (size_t)(st * 64 + r) * C3 + c16;
    *(bf8_t*)&t[r][c16]     = *(const bf8_t*)sp;
    *(bf8_t*)&t[r][c16 + 8] = *(const bf8_t*)(sp + 8);
    __syncthreads();
    short tmp[16];
    #pragma unroll
    for (int i = 0; i < 16; ++i) tmp[i] = t[c16 + i][r];
    short* dp = vt + (size_t)bh * HDIM * S_LEN + (size_t)r * S_LEN + st * 64 + c16;
    *(bf8_t*)dp       = *(bf8_t*)&tmp[0];
    *(bf8_t*)(dp + 8) = *(bf8_t*)&tmp[8];
}

// ---------------------------------------------------------------------------
// bf16 MFMA GEMM (m97 structure) — verified rounds 3-14.
// QSCALE: multiply outputs in cols [0,1024) by CL2E (pre-scales Q so the
// attention inner loop computes exp2(s) with no per-element multiply).
// Column predicate is uniform per tile (1024 % 128 == 0).
// ---------------------------------------------------------------------------
template<bool BF16OUT, bool QSCALE>
__global__ __launch_bounds__(256)
void gemm_mfma(const short* __restrict__ A, const short* __restrict__ Bt,
               const float* __restrict__ bias, void* __restrict__ Cout,
               int M, int N)
{
    constexpr int K = 1024;
    __shared__ __align__(16) short As[128 * 64];
    __shared__ __align__(16) short Bs[128 * 64];

    const int nbx = N / 128;
    const int nwg = (M / 128) * nbx;
    int bid = blockIdx.x;
    bid = (bid & 7) * (nwg >> 3) + (bid >> 3);
    const int by = bid / nbx, bx = bid % nbx;
    const int row0 = by * 128, col0 = bx * 128;

    const int tid  = threadIdx.x;
    const int lane = tid & 63;
    const int w    = tid >> 6;
    const int l15  = lane & 15;
    const int l4   = lane >> 4;
    const int wr   = w >> 1, wc = w & 1;

    f32x4 acc[4][4];
    #pragma unroll
    for (int i = 0; i < 4; ++i)
        #pragma unroll
        for (int j = 0; j < 4; ++j) acc[i][j] = (f32x4){0.f, 0.f, 0.f, 0.f};

    size_t goff[4];
    int    loff[4];
    #pragma unroll
    for (int i = 0; i < 4; ++i) {
        const int o   = (w * 4 + i) * 1024 + lane * 16;
        const int row = o >> 7;
        const int col = (o & 127) ^ ((row & 7) << 4);
        goff[i] = (size_t)row * (K * 2) + col;
        loff[i] = o;
    }
    const char* Ab = (const char*)A  + (size_t)row0 * (K * 2);
    const char* Bb = (const char*)Bt + (size_t)col0 * (K * 2);

    for (int k0 = 0; k0 < K; k0 += 64) {
        __syncthreads();
        #pragma unroll
        for (int i = 0; i < 4; ++i) {
            gload_lds16(Ab + goff[i] + k0 * 2, (char*)As + loff[i]);
            gload_lds16(Bb + goff[i] + k0 * 2, (char*)Bs + loff[i]);
        }
        __syncthreads();

        #pragma unroll
        for (int ks = 0; ks < 2; ++ks) {
            bf8_t af[4], bfr[4];
            #pragma unroll
            for (int mi = 0; mi < 4; ++mi) {
                const int row = wr * 64 + mi * 16 + l15;
                const int off = (row * 128 + ks * 64 + l4 * 16) ^ ((row & 7) << 4);
                af[mi] = *(bf8_t*)((char*)As + off);
            }
            #pragma unroll
            for (int ni = 0; ni < 4; ++ni) {
                const int row = wc * 64 + ni * 16 + l15;
                const int off = (row * 128 + ks * 64 + l4 * 16) ^ ((row & 7) << 4);
                bfr[ni] = *(bf8_t*)((char*)Bs + off);
            }
            #pragma unroll
            for (int mi = 0; mi < 4; ++mi)
                #pragma unroll
                for (int ni = 0; ni < 4; ++ni)
                    acc[mi][ni] = __builtin_amdgcn_mfma_f32_16x16x32_bf16(
                        af[mi], bfr[ni], acc[mi][ni], 0, 0, 0);
        }
    }

    // uniform per block-column-tile: whole 128-col tile is (or isn't) Q
    const float cscale = (QSCALE && col0 < 1024) ? CL2E : 1.0f;

    float bv[4];
    #pragma unroll
    for (int ni = 0; ni < 4; ++ni)
        bv[ni] = bias[col0 + wc * 64 + ni * 16 + l15];

    #pragma unroll
    for (int mi = 0; mi < 4; ++mi)
        #pragma unroll
        for (int r = 0; r < 4; ++r) {
            const int row = row0 + wr * 64 + mi * 16 + l4 * 4 + r;
            #pragma unroll
            for (int ni = 0; ni < 4; ++ni) {
                const int col = col0 + wc * 64 + ni * 16 + l15;
                const float val = (acc[mi][ni][r] + bv[ni]) * cscale;
                if constexpr (BF16OUT)
                    ((short*)Cout)[(size_t)row * N + col] = f2bf(val);
                else
                    ((float*)Cout)[(size_t)row * N + col] = val;
            }
        }
}

// ---------------------------------------------------------------------------
// Flash attention, swapped-QK^T 32x32x16 MFMA.
// Round-15: EXACT r12 body (verified best attn 134.5us: fixed-m softmax,
// XCD grouping, paired q-tiles, KVBLK=64, 2-buf 32KB, shfl_xor P-exchange
// — r13 pipeline and r10/r14 permlane experiments all reverted).
// ONE change: Q arrives pre-scaled by CL2E (gemm1 epilogue), so the
// softmax numerator is exp2(s) directly — deletes 32 v_mul per tile/lane
// from the serial MFMA->exp->pack chain.
// ---------------------------------------------------------------------------
__global__ __launch_bounds__(256)
void attn_mfma32(const short* __restrict__ qkv, const short* __restrict__ vt,
                 short* __restrict__ out)
{
    // XCD grouping: consecutive dispatch ids round-robin XCDs (lin % 8).
    const int lin = blockIdx.x + 16 * blockIdx.y;   // HW dispatch order
    const int xcd = lin & 7;
    const int idx = lin >> 3;                       // 0..63 within XCD
    const int bh  = xcd * 4 + (idx >> 4);           // 4 heads per XCD
    const int g   = idx & 15;                       // pair index 0..15

    const int b   = bh >> 4, h = bh & 15;
    const int tid = threadIdx.x;
    const int lane = tid & 63;
    const int w    = tid >> 6;       // wave 0..3
    const int l31  = lane & 31;
    const int hi   = lane >> 5;      // 0/1

    __shared__ __align__(16) short lds[2][2][64 * 64];   // [buf][K,V][8KB]

    const float NEG = -1e30f;

    const short* qkb = qkv + (size_t)b * S_LEN * C3 + h * HDIM;

    // staging (inverse-swizzled source, linear LDS dest); 4 loads/thread
    const int sr = tid >> 3;                                  // row 0..31
    const int sc = ((tid & 7) * 16) ^ ((sr & 7) << 4);        // swizzled byte col
    const char* srcK = (const char*)(qkb + DM) + (size_t)sr * (C3 * 2) + sc;
    const char* srcV = (const char*)(vt + (size_t)bh * HDIM * S_LEN)
                       + (size_t)sr * (S_LEN * 2) + sc;
    const int ldst = tid * 16;                                // 0..4095

    #pragma unroll 1
    for (int half = 0; half < 2; ++half) {
        const int qb     = half ? g : (31 - g);     // heavy tile first
        const int Q0     = qb * 128;
        const int nkt    = qb * 2 + 2;              // block trip count
        const int qmin_w = Q0 + w * 32;
        const int qmax_w = qmin_w + 31;
        const int q_g    = qmin_w + l31;            // this lane's q row
        const int nkt_w  = (qmax_w >> 6) + 1;       // wave's active tiles

        // ---- Q fragments (B-operand): col=q=l31, d = 16*ds + 8*hi + j ----
        bf8_t qf[4];
        {
            const short* qp = qkb + (size_t)q_g * C3 + hi * 8;
            qf[0] = *(const bf8_t*)(qp);
            qf[1] = *(const bf8_t*)(qp + 16);
            qf[2] = *(const bf8_t*)(qp + 32);
            qf[3] = *(const bf8_t*)(qp + 48);
        }

        f32x16 o0, o1;
        #pragma unroll
        for (int r = 0; r < 16; ++r) { o0[r] = 0.f; o1[r] = 0.f; }
        float l = 0.f;    // lane-local half-sum; cross-half combined in epilogue

        // prologue: stage kt=0 into buf0
        gload_lds16(srcK,                     (char*)lds + ldst);
        gload_lds16(srcK + 32 * (C3 * 2),     (char*)lds + 4096 + ldst);
        gload_lds16(srcV,                     (char*)lds + 8192 + ldst);
        gload_lds16(srcV + 32 * (S_LEN * 2),  (char*)lds + 12288 + ldst);
        __syncthreads();

        for (int kt = 0; kt < nkt; ++kt) {
            const int cur = kt & 1;
            // stage next tile into other buffer (loads fly during compute)
            if (kt + 1 < nkt) {
                const char* sK = srcK + (size_t)(kt + 1) * 64 * (C3 * 2);
                const char* sV = srcV + (size_t)(kt + 1) * 64 * 2;
                char* dstb = (char*)lds + (cur ^ 1) * 16384;
                gload_lds16(sK,                    dstb + ldst);
                gload_lds16(sK + 32 * (C3 * 2),    dstb + 4096 + ldst);
                gload_lds16(sV,                    dstb + 8192 + ldst);
                gload_lds16(sV + 32 * (S_LEN * 2), dstb + 12288 + ldst);
            }

            if (kt < nkt_w) {
                const char* Kb = (char*)lds + cur * 16384;
                const char* Vb = Kb + 8192;
                const int kb0 = kt * 64;
                const bool act1 = (kb0 + 32) <= qmax_w;

                // ---- S^T = mfma(K, Q): acc rows = k (crow), cols = q ----
                // (Q pre-scaled: s is already C*score)
                f32x16 s0, s1;
                #pragma unroll
                for (int r = 0; r < 16; ++r) { s0[r] = 0.f; s1[r] = NEG; }
                __builtin_amdgcn_s_setprio(1);
                #pragma unroll
                for (int ds = 0; ds < 4; ++ds) {
                    const int R0 = l31;
                    const int off0 = (R0 * 128 + ds * 32 + hi * 16) ^ ((R0 & 7) << 4);
                    bf8_t kf = *(const bf8_t*)(Kb + off0);
                    s0 = __builtin_amdgcn_mfma_f32_32x32x16_bf16(kf, qf[ds], s0, 0, 0, 0);
                }
                if (act1) {
                    #pragma unroll
                    for (int r = 0; r < 16; ++r) s1[r] = 0.f;
                    #pragma unroll
                    for (int ds = 0; ds < 4; ++ds) {
                        const int R1 = 32 + l31;
                        const int off1 = (R1 * 128 + ds * 32 + hi * 16) ^ ((R1 & 7) << 4);
                        bf8_t kf = *(const bf8_t*)(Kb + off1);
                        s1 = __builtin_amdgcn_mfma_f32_32x32x16_bf16(kf, qf[ds], s1, 0, 0, 0);
                    }
                }
                __builtin_amdgcn_s_setprio(0);

                // ---- causal mask (k = kb0 + 32t + crow(r,hi)) ----
                if (kb0 + 31 > qmin_w) {
                    #pragma unroll
                    for (int r = 0; r < 16; ++r) {
                        const int k = kb0 + 4 * hi + ((r & 3) + 8 * (r >> 2));
                        if (k > q_g) s0[r] = NEG;
                    }
                }
                if (act1 && (kb0 + 63 > qmin_w)) {
                    #pragma unroll
                    for (int r = 0; r < 16; ++r) {
                        const int k = kb0 + 32 + 4 * hi + ((r & 3) + 8 * (r >> 2));
                        if (k > q_g) s1[r] = NEG;
                    }
                }

                // ---- fixed-shift softmax numerator: p = exp2(s) ----
                // (masked -> exp2(-1e30) = 0 exactly)
                #pragma unroll
                for (int r = 0; r < 16; ++r) s0[r] = fexp2(s0[r]);
                #pragma unroll
                for (int r = 0; r < 16; ++r) s1[r] = fexp2(s1[r]);

                l += vsum16(s0) + vsum16(s1);   // lane-local half-sum

                // ---- pack P (HW cvt_pk); 8 shfl_xor exchange; PV ----
                unsigned W0[2][4], W1[2][4];
                #pragma unroll
                for (int gg = 0; gg < 4; ++gg) {
                    W0[0][gg] = cvtpk(s0[4 * gg], s0[4 * gg + 1]);
                    W1[0][gg] = cvtpk(s0[4 * gg + 2], s0[4 * gg + 3]);
                    W0[1][gg] = cvtpk(s1[4 * gg], s1[4 * gg + 1]);
                    W1[1][gg] = cvtpk(s1[4 * gg + 2], s1[4 * gg + 3]);
                }

                #pragma unroll
                for (int c = 0; c < 4; ++c) {
                    const int t  = c >> 1;
                    const int gA = 2 * (c & 1);
                    const int gB = gA + 1;
                    const unsigned rx0 = __shfl_xor(hi ? W0[t][gA] : W0[t][gB], 32);
                    const unsigned rx1 = __shfl_xor(hi ? W1[t][gA] : W1[t][gB], 32);
                    union { unsigned u[4]; bf8_t v; } pf;
                    pf.u[0] = hi ? rx0 : W0[t][gA];
                    pf.u[1] = hi ? rx1 : W1[t][gA];
                    pf.u[2] = hi ? W0[t][gB] : rx0;
                    pf.u[3] = hi ? W1[t][gB] : rx1;

                    __builtin_amdgcn_s_setprio(1);
                    {
                        const int R = l31;
                        const int off = (R * 128 + c * 32 + hi * 16) ^ ((R & 7) << 4);
                        bf8_t vf = *(const bf8_t*)(Vb + off);
                        o0 = __builtin_amdgcn_mfma_f32_32x32x16_bf16(pf.v, vf, o0, 0, 0, 0);
                    }
                    {
                        const int R = 32 + l31;
                        const int off = (R * 128 + c * 32 + hi * 16) ^ ((R & 7) << 4);
                        bf8_t vf = *(const bf8_t*)(Vb + off);
                        o1 = __builtin_amdgcn_mfma_f32_32x32x16_bf16(pf.v, vf, o1, 0, 0, 0);
                    }
                    __builtin_amdgcn_s_setprio(0);
                }
            }
            __syncthreads();   // next buffer staged; all reads of cur done
        }

        // ---- epilogue: combine half-sums, normalize, store ----
        const float lt = l + __shfl_xor(l, 32);
        const float inv = 1.f / lt;
        #pragma unroll
        for (int r = 0; r < 16; ++r) {
            const int cr = 4 * hi + ((r & 3) + 8 * (r >> 2));
            const float iv = __shfl(inv, cr);
            const int row = Q0 + w * 32 + cr;
            short* op = out + (size_t)(b * S_LEN + row) * DM + h * HDIM + l31;
            op[0]  = f2bf(o0[r] * iv);
            op[32] = f2bf(o1[r] * iv);
        }
    }
}

// ---------------------------------------------------------------------------
extern "C" void kernel_launch(void* const* d_in, const int* in_sizes, int n_in,
                              void* d_out, int out_size, void* d_ws, size_t ws_size,
                              hipStream_t stream)
{
    const float* x     = (const float*)d_in[0];
    const float* w_qkv = (const float*)d_in[1];
    const float* b_qkv = (const float*)d_in[2];
    const float* w_out = (const float*)d_in[3];
    const float* b_out = (const float*)d_in[4];
    float* out = (float*)d_out;

    const int M = 2 * S_LEN;   // 8192 tokens

    char* ws = (char*)d_ws;
    short* qkvb  = (short*)(ws);                    // [8192,3072] bf16  50.3MB
    short* attnb = (short*)(ws + 50331648);         // [8192,1024] bf16  16.8MB
    short* xb    = (short*)(ws + 67108864);         // [8192,1024] bf16  16.8MB
    short* wqkvT = (short*)(ws + 83886080);         // [3072,1024] bf16   6.3MB
    short* woutT = (short*)(ws + 90177536);         // [1024,1024] bf16   2.1MB
    short* vtb   = (short*)(ws + 92274688);         // [32][64][4096]    16.8MB

    // 0) casts / transposes to bf16
    cast_f32_bf16<<<dim3((M * DM / 8 + 255) / 256), 256, 0, stream>>>(x, xb, M * DM / 8);
    transpose_cast<<<dim3(C3 / 32, DM / 32), 256, 0, stream>>>(w_qkv, wqkvT, DM, C3);
    transpose_cast<<<dim3(DM / 32, DM / 32), 256, 0, stream>>>(w_out, woutT, DM, DM);

    // 1) QKV projection (bf16 MFMA), Q pre-scaled by CL2E -> bf16
    gemm_mfma<true, true><<<dim3((M / 128) * (C3 / 128)), 256, 0, stream>>>(
        xb, wqkvT, b_qkv, qkvb, M, C3);

    // 1b) V -> V^T layout for attention staging
    transpose_v<<<dim3(S_LEN / 64, 2 * NHEAD), 256, 0, stream>>>(qkvb, vtb);

    // 2) causal flash attention (fixed-m, XCD-grouped, pre-scaled Q) -> bf16
    attn_mfma32<<<dim3(16, 2 * NHEAD), 256, 0, stream>>>(qkvb, vtb, attnb);

    // 3) output projection (bf16 MFMA) -> fp32
    gemm_mfma<false, false><<<dim3((M / 128) * (DM / 128)), 256, 0, stream>>>(
        attnb, woutT, b_out, out, M, DM);
}